// Round 4
// baseline (1561.579 us; speedup 1.0000x reference)
//
#include <hip/hip_runtime.h>

#define N_NODES 100000
#define E_EDGES 1600000
#define IN_C 128
#define HID_C 64
#define OUT_C 32
#define BNODES 64                                   // nodes per bucket (dst>>6)
#define NBUCK ((N_NODES + BNODES - 1) / BNODES)     // 1563

// ---- bucket histogram: bcnt[dst>>6]++ (1563 L2-resident counters) ----
__global__ void bucket_count_kernel(const int* __restrict__ dst, int* __restrict__ bcnt) {
    int e = blockIdx.x * blockDim.x + threadIdx.x;
    if (e < E_EDGES) atomicAdd(&bcnt[dst[e] >> 6], 1);
}

// ---- single-block exclusive scan of 1563 bucket counts -> boffs; cursor back into bcnt ----
__global__ __launch_bounds__(1024) void bucket_scan_kernel(int* __restrict__ bcnt,
                                                           int* __restrict__ boffs) {
    __shared__ int s[1024];
    int total = 0;
    for (int base = 0; base < NBUCK; base += 1024) {
        int i = base + threadIdx.x;
        int v = (i < NBUCK) ? bcnt[i] : 0;
        s[threadIdx.x] = v;
        __syncthreads();
        for (int off = 1; off < 1024; off <<= 1) {
            int t = (threadIdx.x >= off) ? s[threadIdx.x - off] : 0;
            __syncthreads();
            s[threadIdx.x] += t;
            __syncthreads();
        }
        if (i < NBUCK) {
            int ex = total + s[threadIdx.x] - v;   // exclusive prefix
            boffs[i] = ex;
            bcnt[i]  = ex;                         // becomes the fill cursor
        }
        total += s[1023];
        __syncthreads();
    }
    if (threadIdx.x == 0) boffs[NBUCK] = E_EDGES;
}

// ---- bucket fill: pairs[cursor[dst>>6]++] = (src<<8)|(dst&255). Hot cursor-line set
//      = 1563 lines (~100 KB, L2-resident) -> dense writeback ----
__global__ void bucket_fill_kernel(const int* __restrict__ src, const int* __restrict__ dst,
                                   int* __restrict__ cursor, unsigned* __restrict__ pairs) {
    int e = blockIdx.x * blockDim.x + threadIdx.x;
    if (e < E_EDGES) {
        int d = dst[e];
        int pos = atomicAdd(&cursor[d >> 6], 1);
        pairs[pos] = ((unsigned)src[e] << 8) | (unsigned)(d & 255);
    }
}

// ---- deg + dinv from bucketed pairs: one block per 4 buckets (256 aligned nodes),
//      LDS histogram, dense dinv write. Replaces 100k-counter global atomics. ----
__global__ __launch_bounds__(256) void deg_dinv_kernel(const int* __restrict__ boffs,
                                                       const unsigned* __restrict__ pairs,
                                                       float* __restrict__ dinv) {
    __shared__ int hist[256];
    const int b4 = blockIdx.x;
    hist[threadIdx.x] = 0;
    __syncthreads();
    const int beg = boffs[b4 * 4];
    const int end = boffs[min(b4 * 4 + 4, NBUCK)];
    for (int j = beg + threadIdx.x; j < end; j += 256)
        atomicAdd(&hist[pairs[j] & 255], 1);
    __syncthreads();
    int node = b4 * 256 + threadIdx.x;
    if (node < N_NODES) dinv[node] = rsqrtf((float)hist[threadIdx.x] + 1.0f);
}

// ---- hs = dinv[row] * (x @ W1) : register-tiled 4 rows x 8 cols per thread ----
__global__ __launch_bounds__(256) void gemm1_kernel(const float* __restrict__ x,
                                                    const float* __restrict__ W1,
                                                    const float* __restrict__ dinv,
                                                    float* __restrict__ hs) {
    __shared__ float sW[IN_C * HID_C];
    for (int i = threadIdx.x; i < IN_C * HID_C; i += 256) sW[i] = W1[i];
    __syncthreads();
    const int cg = (threadIdx.x & 7) * 8;
    const int row0 = blockIdx.x * 128 + (threadIdx.x >> 3) * 4;
    float acc[4][8];
#pragma unroll
    for (int r = 0; r < 4; ++r)
#pragma unroll
        for (int c = 0; c < 8; ++c) acc[r][c] = 0.f;

    int rr[4];
#pragma unroll
    for (int r = 0; r < 4; ++r) rr[r] = min(row0 + r, N_NODES - 1);

    const float4* x4 = (const float4*)x;
#pragma unroll 2
    for (int k4 = 0; k4 < IN_C / 4; ++k4) {
        float4 xv[4];
#pragma unroll
        for (int r = 0; r < 4; ++r) xv[r] = x4[(size_t)rr[r] * (IN_C / 4) + k4];
        float xs[4][4];
#pragma unroll
        for (int r = 0; r < 4; ++r) {
            xs[r][0] = xv[r].x; xs[r][1] = xv[r].y; xs[r][2] = xv[r].z; xs[r][3] = xv[r].w;
        }
#pragma unroll
        for (int kk = 0; kk < 4; ++kk) {
            const float4* wp = (const float4*)(sW + (k4 * 4 + kk) * HID_C + cg);
            float4 w0 = wp[0], w1 = wp[1];
            float wv[8] = {w0.x, w0.y, w0.z, w0.w, w1.x, w1.y, w1.z, w1.w};
#pragma unroll
            for (int r = 0; r < 4; ++r)
#pragma unroll
                for (int c = 0; c < 8; ++c)
                    acc[r][c] = fmaf(xs[r][kk], wv[c], acc[r][c]);
        }
    }
#pragma unroll
    for (int r = 0; r < 4; ++r) {
        int row = row0 + r;
        if (row < N_NODES) {
            float dv = dinv[row];
            float4 o0, o1;
            o0.x = acc[r][0] * dv; o0.y = acc[r][1] * dv; o0.z = acc[r][2] * dv; o0.w = acc[r][3] * dv;
            o1.x = acc[r][4] * dv; o1.y = acc[r][5] * dv; o1.z = acc[r][6] * dv; o1.w = acc[r][7] * dv;
            float4* op = (float4*)(hs + (size_t)row * HID_C + cg);
            op[0] = o0; op[1] = o1;
        }
    }
}

// ---- layer-1 aggregate: one block per 64-node bucket, LDS tile accumulation.
//      wave = 1 edge x 64 channels; ds_add_f32 (2-way bank alias = free); fused finalize ----
__global__ __launch_bounds__(256) void agg1_kernel(const int* __restrict__ boffs,
                                                   const unsigned* __restrict__ pairs,
                                                   const float* __restrict__ hs,
                                                   const float* __restrict__ dinv,
                                                   const float* __restrict__ b1,
                                                   float* __restrict__ h2) {
    __shared__ float tile[BNODES * HID_C];     // 16 KB
    const int b = blockIdx.x;
    const int wave = threadIdx.x >> 6, lane = threadIdx.x & 63;
    for (int i = threadIdx.x; i < BNODES * HID_C; i += 256) tile[i] = 0.f;
    __syncthreads();
    const int beg = boffs[b], end = boffs[b + 1];
    int j = beg + wave;
    for (; j + 12 < end; j += 16) {            // 4 waves x 4-deep unroll
        unsigned p0 = pairs[j], p1 = pairs[j + 4], p2 = pairs[j + 8], p3 = pairs[j + 12];
        float v0 = hs[(p0 >> 8) * HID_C + lane];
        float v1 = hs[(p1 >> 8) * HID_C + lane];
        float v2 = hs[(p2 >> 8) * HID_C + lane];
        float v3 = hs[(p3 >> 8) * HID_C + lane];
        atomicAdd(&tile[(p0 & 63) * HID_C + lane], v0);
        atomicAdd(&tile[(p1 & 63) * HID_C + lane], v1);
        atomicAdd(&tile[(p2 & 63) * HID_C + lane], v2);
        atomicAdd(&tile[(p3 & 63) * HID_C + lane], v3);
    }
    for (; j < end; j += 4) {
        unsigned p = pairs[j];
        atomicAdd(&tile[(p & 63) * HID_C + lane], hs[(p >> 8) * HID_C + lane]);
    }
    __syncthreads();
    const int nbase = b * BNODES;
    const int nmax = min(BNODES, N_NODES - nbase);
    for (int i = threadIdx.x; i < nmax * HID_C; i += 256) {
        int node = nbase + (i >> 6), c = i & 63;
        float v = dinv[node] * (tile[i] + hs[node * HID_C + c]) + b1[c];
        h2[node * HID_C + c] = fmaxf(v, 0.f);
    }
}

// ---- gs = dinv[row] * (h2 @ W2) : register-tiled 2 rows x 8 cols per thread ----
__global__ __launch_bounds__(256) void gemm2_kernel(const float* __restrict__ h2,
                                                    const float* __restrict__ W2,
                                                    const float* __restrict__ dinv,
                                                    float* __restrict__ gs) {
    __shared__ float sW[HID_C * OUT_C];
    for (int i = threadIdx.x; i < HID_C * OUT_C; i += 256) sW[i] = W2[i];
    __syncthreads();
    const int cg = (threadIdx.x & 3) * 8;
    const int row0 = blockIdx.x * 128 + (threadIdx.x >> 2) * 2;
    float acc[2][8];
#pragma unroll
    for (int r = 0; r < 2; ++r)
#pragma unroll
        for (int c = 0; c < 8; ++c) acc[r][c] = 0.f;

    int rr[2];
#pragma unroll
    for (int r = 0; r < 2; ++r) rr[r] = min(row0 + r, N_NODES - 1);

    const float4* h4 = (const float4*)h2;
#pragma unroll 2
    for (int k4 = 0; k4 < HID_C / 4; ++k4) {
        float4 xv[2];
#pragma unroll
        for (int r = 0; r < 2; ++r) xv[r] = h4[(size_t)rr[r] * (HID_C / 4) + k4];
        float xs[2][4];
#pragma unroll
        for (int r = 0; r < 2; ++r) {
            xs[r][0] = xv[r].x; xs[r][1] = xv[r].y; xs[r][2] = xv[r].z; xs[r][3] = xv[r].w;
        }
#pragma unroll
        for (int kk = 0; kk < 4; ++kk) {
            const float4* wp = (const float4*)(sW + (k4 * 4 + kk) * OUT_C + cg);
            float4 w0 = wp[0], w1 = wp[1];
            float wv[8] = {w0.x, w0.y, w0.z, w0.w, w1.x, w1.y, w1.z, w1.w};
#pragma unroll
            for (int r = 0; r < 2; ++r)
#pragma unroll
                for (int c = 0; c < 8; ++c)
                    acc[r][c] = fmaf(xs[r][kk], wv[c], acc[r][c]);
        }
    }
#pragma unroll
    for (int r = 0; r < 2; ++r) {
        int row = row0 + r;
        if (row < N_NODES) {
            float dv = dinv[row];
            float4 o0, o1;
            o0.x = acc[r][0] * dv; o0.y = acc[r][1] * dv; o0.z = acc[r][2] * dv; o0.w = acc[r][3] * dv;
            o1.x = acc[r][4] * dv; o1.y = acc[r][5] * dv; o1.z = acc[r][6] * dv; o1.w = acc[r][7] * dv;
            float4* op = (float4*)(gs + (size_t)row * OUT_C + cg);
            op[0] = o0; op[1] = o1;
        }
    }
}

// ---- layer-2 aggregate: one block per 2 buckets (128 aligned nodes, contiguous range).
//      half-wave = 1 edge x 32 channels; fused finalize ----
__global__ __launch_bounds__(256) void agg2_kernel(const int* __restrict__ boffs,
                                                   const unsigned* __restrict__ pairs,
                                                   const float* __restrict__ gs,
                                                   const float* __restrict__ dinv,
                                                   const float* __restrict__ b2,
                                                   float* __restrict__ out) {
    __shared__ float tile[128 * OUT_C];        // 16 KB
    const int b = blockIdx.x;
    const int wave = threadIdx.x >> 6, lane = threadIdx.x & 63;
    const int eh = lane >> 5, c = lane & 31;
    for (int i = threadIdx.x; i < 128 * OUT_C; i += 256) tile[i] = 0.f;
    __syncthreads();
    const int beg = boffs[2 * b];
    const int end = boffs[min(2 * b + 2, NBUCK)];
    int j = beg + wave * 2 + eh;               // 8 edge-streams (4 waves x 2 half-waves)
    for (; j + 24 < end; j += 32) {
        unsigned p0 = pairs[j], p1 = pairs[j + 8], p2 = pairs[j + 16], p3 = pairs[j + 24];
        float v0 = gs[(p0 >> 8) * OUT_C + c];
        float v1 = gs[(p1 >> 8) * OUT_C + c];
        float v2 = gs[(p2 >> 8) * OUT_C + c];
        float v3 = gs[(p3 >> 8) * OUT_C + c];
        atomicAdd(&tile[(p0 & 127) * OUT_C + c], v0);
        atomicAdd(&tile[(p1 & 127) * OUT_C + c], v1);
        atomicAdd(&tile[(p2 & 127) * OUT_C + c], v2);
        atomicAdd(&tile[(p3 & 127) * OUT_C + c], v3);
    }
    for (; j < end; j += 8) {
        unsigned p = pairs[j];
        atomicAdd(&tile[(p & 127) * OUT_C + c], gs[(p >> 8) * OUT_C + c]);
    }
    __syncthreads();
    const int nbase = b * 128;
    const int nmax = min(128, N_NODES - nbase);
    for (int i = threadIdx.x; i < nmax * OUT_C; i += 256) {
        int node = nbase + (i >> 5), cc = i & 31;
        out[node * OUT_C + cc] = dinv[node] * (tile[i] + gs[node * OUT_C + cc]) + b2[cc];
    }
}

extern "C" void kernel_launch(void* const* d_in, const int* in_sizes, int n_in,
                              void* d_out, int out_size, void* d_ws, size_t ws_size,
                              hipStream_t stream) {
    const float* x  = (const float*)d_in[0];   // [N,128]
    const int*   ei = (const int*)d_in[1];     // [2,E]
    const float* W1 = (const float*)d_in[2];   // [128,64]
    const float* b1 = (const float*)d_in[3];   // [64]
    const float* W2 = (const float*)d_in[4];   // [64,32]
    const float* b2 = (const float*)d_in[5];   // [32]
    float* out = (float*)d_out;                // [N,32]

    const int* srcv = ei;
    const int* dstv = ei + E_EDGES;

    // workspace layout (~58.1 MB)
    float* dinv = (float*)d_ws;                          // N
    float* hs   = dinv + N_NODES;                        // N*64 (reused as gs after agg1)
    float* h2   = hs + (size_t)N_NODES * HID_C;          // N*64
    int* bcnt      = (int*)(h2 + (size_t)N_NODES * HID_C); // NBUCK (counts, then cursor)
    int* boffs     = bcnt + NBUCK;                       // NBUCK+1
    unsigned* pairs = (unsigned*)(boffs + NBUCK + 1);    // E
    float* gs = hs;

    hipMemsetAsync(bcnt, 0, NBUCK * sizeof(int), stream);

    // bucketed edge list (64-node granularity)
    bucket_count_kernel<<<(E_EDGES + 255) / 256, 256, 0, stream>>>(dstv, bcnt);
    bucket_scan_kernel<<<1, 1024, 0, stream>>>(bcnt, boffs);
    bucket_fill_kernel<<<(E_EDGES + 255) / 256, 256, 0, stream>>>(srcv, dstv, bcnt, pairs);
    deg_dinv_kernel<<<(NBUCK + 3) / 4, 256, 0, stream>>>(boffs, pairs, dinv);

    // layer 1
    gemm1_kernel<<<(N_NODES + 127) / 128, 256, 0, stream>>>(x, W1, dinv, hs);
    agg1_kernel<<<NBUCK, 256, 0, stream>>>(boffs, pairs, hs, dinv, b1, h2);

    // layer 2
    gemm2_kernel<<<(N_NODES + 127) / 128, 256, 0, stream>>>(h2, W2, dinv, gs);
    agg2_kernel<<<(NBUCK + 1) / 2, 256, 0, stream>>>(boffs, pairs, gs, dinv, b2, out);
}

// Round 5
// 726.411 us; speedup vs baseline: 2.1497x; 2.1497x over previous
//
#include <hip/hip_runtime.h>

#define N_NODES 100000
#define E_EDGES 1600000
#define IN_C 128
#define HID_C 64
#define OUT_C 32
#define BNODES 64                                   // nodes per bucket (dst>>6)
#define NBUCK ((N_NODES + BNODES - 1) / BNODES)     // 1563
#define MAXB 2048                                   // bucket cap (mean 1024, sigma 32 -> 32 sigma)

// ---- bucket histogram: bcnt[dst>>6]++ (1563 L2-resident counters) ----
__global__ void bucket_count_kernel(const int* __restrict__ dst, int* __restrict__ bcnt) {
    int e = blockIdx.x * blockDim.x + threadIdx.x;
    if (e < E_EDGES) atomicAdd(&bcnt[dst[e] >> 6], 1);
}

// ---- single-block exclusive scan of 1563 bucket counts -> boffs; cursor back into bcnt ----
__global__ __launch_bounds__(1024) void bucket_scan_kernel(int* __restrict__ bcnt,
                                                           int* __restrict__ boffs) {
    __shared__ int s[1024];
    int total = 0;
    for (int base = 0; base < NBUCK; base += 1024) {
        int i = base + threadIdx.x;
        int v = (i < NBUCK) ? bcnt[i] : 0;
        s[threadIdx.x] = v;
        __syncthreads();
        for (int off = 1; off < 1024; off <<= 1) {
            int t = (threadIdx.x >= off) ? s[threadIdx.x - off] : 0;
            __syncthreads();
            s[threadIdx.x] += t;
            __syncthreads();
        }
        if (i < NBUCK) {
            int ex = total + s[threadIdx.x] - v;
            boffs[i] = ex;
            bcnt[i]  = ex;                         // becomes the fill cursor
        }
        total += s[1023];
        __syncthreads();
    }
    if (threadIdx.x == 0) boffs[NBUCK] = E_EDGES;
}

// ---- bucket fill: pairs[cursor[dst>>6]++] = (src<<6)|(dst&63) ----
__global__ void bucket_fill_kernel(const int* __restrict__ src, const int* __restrict__ dst,
                                   int* __restrict__ cursor, unsigned* __restrict__ pairs) {
    int e = blockIdx.x * blockDim.x + threadIdx.x;
    if (e < E_EDGES) {
        int d = dst[e];
        int pos = atomicAdd(&cursor[d >> 6], 1);
        pairs[pos] = ((unsigned)src[e] << 6) | (unsigned)(d & 63);
    }
}

// ---- per-bucket counting sort -> node-level CSR, in place.
//      One block per bucket: LDS stage (~1024 edges), 64-bin hist+scan,
//      writes row_ptr[node], dinv[node], and pairs[beg+pos] = src (sorted by node).
//      All traffic dense / L2-resident — replaces the 105 MB-waste global build_col. ----
__global__ __launch_bounds__(256) void bucket_sort_kernel(const int* __restrict__ boffs,
                                                          unsigned* __restrict__ pairs,
                                                          int* __restrict__ row_ptr,
                                                          float* __restrict__ dinv) {
    __shared__ unsigned sp[MAXB];
    __shared__ int hist[BNODES], scn[BNODES], cur[BNODES];
    const int b = blockIdx.x;
    const int beg = boffs[b], end = boffs[b + 1];
    const int cnt = end - beg;
    if (threadIdx.x < BNODES) hist[threadIdx.x] = 0;
    __syncthreads();
    for (int j = threadIdx.x; j < cnt; j += 256) {
        unsigned p = pairs[beg + j];
        sp[j] = p;
        atomicAdd(&hist[p & 63], 1);
    }
    __syncthreads();
    if (threadIdx.x < BNODES) scn[threadIdx.x] = hist[threadIdx.x];
    __syncthreads();
    for (int off = 1; off < BNODES; off <<= 1) {
        int t = 0;
        if (threadIdx.x < BNODES && threadIdx.x >= off) t = scn[threadIdx.x - off];
        __syncthreads();
        if (threadIdx.x < BNODES) scn[threadIdx.x] += t;
        __syncthreads();
    }
    if (threadIdx.x < BNODES) {
        int ex = scn[threadIdx.x] - hist[threadIdx.x];   // exclusive
        cur[threadIdx.x] = ex;
        int node = b * BNODES + threadIdx.x;
        if (node < N_NODES) {
            row_ptr[node] = beg + ex;
            dinv[node] = rsqrtf((float)hist[threadIdx.x] + 1.0f);
        }
    }
    if (threadIdx.x == 0 && b == NBUCK - 1) row_ptr[N_NODES] = E_EDGES;
    __syncthreads();
    for (int j = threadIdx.x; j < cnt; j += 256) {
        unsigned p = sp[j];
        int pos = atomicAdd(&cur[p & 63], 1);
        pairs[beg + pos] = p >> 6;                      // now plain src index
    }
}

// ---- hs = dinv[row] * (x @ W1) : register-tiled 4 rows x 8 cols per thread ----
__global__ __launch_bounds__(256) void gemm1_kernel(const float* __restrict__ x,
                                                    const float* __restrict__ W1,
                                                    const float* __restrict__ dinv,
                                                    float* __restrict__ hs) {
    __shared__ float sW[IN_C * HID_C];
    for (int i = threadIdx.x; i < IN_C * HID_C; i += 256) sW[i] = W1[i];
    __syncthreads();
    const int cg = (threadIdx.x & 7) * 8;
    const int row0 = blockIdx.x * 128 + (threadIdx.x >> 3) * 4;
    float acc[4][8];
#pragma unroll
    for (int r = 0; r < 4; ++r)
#pragma unroll
        for (int c = 0; c < 8; ++c) acc[r][c] = 0.f;

    int rr[4];
#pragma unroll
    for (int r = 0; r < 4; ++r) rr[r] = min(row0 + r, N_NODES - 1);

    const float4* x4 = (const float4*)x;
#pragma unroll 2
    for (int k4 = 0; k4 < IN_C / 4; ++k4) {
        float4 xv[4];
#pragma unroll
        for (int r = 0; r < 4; ++r) xv[r] = x4[(size_t)rr[r] * (IN_C / 4) + k4];
        float xs[4][4];
#pragma unroll
        for (int r = 0; r < 4; ++r) {
            xs[r][0] = xv[r].x; xs[r][1] = xv[r].y; xs[r][2] = xv[r].z; xs[r][3] = xv[r].w;
        }
#pragma unroll
        for (int kk = 0; kk < 4; ++kk) {
            const float4* wp = (const float4*)(sW + (k4 * 4 + kk) * HID_C + cg);
            float4 w0 = wp[0], w1 = wp[1];
            float wv[8] = {w0.x, w0.y, w0.z, w0.w, w1.x, w1.y, w1.z, w1.w};
#pragma unroll
            for (int r = 0; r < 4; ++r)
#pragma unroll
                for (int c = 0; c < 8; ++c)
                    acc[r][c] = fmaf(xs[r][kk], wv[c], acc[r][c]);
        }
    }
#pragma unroll
    for (int r = 0; r < 4; ++r) {
        int row = row0 + r;
        if (row < N_NODES) {
            float dv = dinv[row];
            float4 o0, o1;
            o0.x = acc[r][0] * dv; o0.y = acc[r][1] * dv; o0.z = acc[r][2] * dv; o0.w = acc[r][3] * dv;
            o1.x = acc[r][4] * dv; o1.y = acc[r][5] * dv; o1.z = acc[r][6] * dv; o1.w = acc[r][7] * dv;
            float4* op = (float4*)(hs + (size_t)row * HID_C + cg);
            op[0] = o0; op[1] = o1;
        }
    }
}

// ---- layer-1 aggregate: one wave per node (64 ch lanes), CSR pull, 8/2/1 unroll ----
__global__ void agg1_kernel(const int* __restrict__ row_ptr, const int* __restrict__ col,
                            const float* __restrict__ hs, const float* __restrict__ dinv,
                            const float* __restrict__ b1, float* __restrict__ h2) {
    const int node = blockIdx.x * 4 + (threadIdx.x >> 6);
    const int c = threadIdx.x & 63;
    if (node >= N_NODES) return;
    const int beg = row_ptr[node], end = row_ptr[node + 1];
    float acc = hs[node * HID_C + c];     // self loop
    int j = beg;
    for (; j + 7 < end; j += 8) {         // 8 independent gathers in flight
        int s0 = col[j],     s1 = col[j + 1], s2 = col[j + 2], s3 = col[j + 3];
        int s4 = col[j + 4], s5 = col[j + 5], s6 = col[j + 6], s7 = col[j + 7];
        float v0 = hs[s0 * HID_C + c], v1 = hs[s1 * HID_C + c];
        float v2 = hs[s2 * HID_C + c], v3 = hs[s3 * HID_C + c];
        float v4 = hs[s4 * HID_C + c], v5 = hs[s5 * HID_C + c];
        float v6 = hs[s6 * HID_C + c], v7 = hs[s7 * HID_C + c];
        acc += ((v0 + v1) + (v2 + v3)) + ((v4 + v5) + (v6 + v7));
    }
    for (; j + 1 < end; j += 2) {
        int s0 = col[j], s1 = col[j + 1];
        float v0 = hs[s0 * HID_C + c], v1 = hs[s1 * HID_C + c];
        acc += v0 + v1;
    }
    if (j < end) acc += hs[col[j] * HID_C + c];
    float v = dinv[node] * acc + b1[c];
    h2[node * HID_C + c] = fmaxf(v, 0.f);
}

// ---- gs = dinv[row] * (h2 @ W2) : register-tiled 2 rows x 8 cols per thread ----
__global__ __launch_bounds__(256) void gemm2_kernel(const float* __restrict__ h2,
                                                    const float* __restrict__ W2,
                                                    const float* __restrict__ dinv,
                                                    float* __restrict__ gs) {
    __shared__ float sW[HID_C * OUT_C];
    for (int i = threadIdx.x; i < HID_C * OUT_C; i += 256) sW[i] = W2[i];
    __syncthreads();
    const int cg = (threadIdx.x & 3) * 8;
    const int row0 = blockIdx.x * 128 + (threadIdx.x >> 2) * 2;
    float acc[2][8];
#pragma unroll
    for (int r = 0; r < 2; ++r)
#pragma unroll
        for (int c = 0; c < 8; ++c) acc[r][c] = 0.f;

    int rr[2];
#pragma unroll
    for (int r = 0; r < 2; ++r) rr[r] = min(row0 + r, N_NODES - 1);

    const float4* h4 = (const float4*)h2;
#pragma unroll 2
    for (int k4 = 0; k4 < HID_C / 4; ++k4) {
        float4 xv[2];
#pragma unroll
        for (int r = 0; r < 2; ++r) xv[r] = h4[(size_t)rr[r] * (HID_C / 4) + k4];
        float xs[2][4];
#pragma unroll
        for (int r = 0; r < 2; ++r) {
            xs[r][0] = xv[r].x; xs[r][1] = xv[r].y; xs[r][2] = xv[r].z; xs[r][3] = xv[r].w;
        }
#pragma unroll
        for (int kk = 0; kk < 4; ++kk) {
            const float4* wp = (const float4*)(sW + (k4 * 4 + kk) * OUT_C + cg);
            float4 w0 = wp[0], w1 = wp[1];
            float wv[8] = {w0.x, w0.y, w0.z, w0.w, w1.x, w1.y, w1.z, w1.w};
#pragma unroll
            for (int r = 0; r < 2; ++r)
#pragma unroll
                for (int c = 0; c < 8; ++c)
                    acc[r][c] = fmaf(xs[r][kk], wv[c], acc[r][c]);
        }
    }
#pragma unroll
    for (int r = 0; r < 2; ++r) {
        int row = row0 + r;
        if (row < N_NODES) {
            float dv = dinv[row];
            float4 o0, o1;
            o0.x = acc[r][0] * dv; o0.y = acc[r][1] * dv; o0.z = acc[r][2] * dv; o0.w = acc[r][3] * dv;
            o1.x = acc[r][4] * dv; o1.y = acc[r][5] * dv; o1.z = acc[r][6] * dv; o1.w = acc[r][7] * dv;
            float4* op = (float4*)(gs + (size_t)row * OUT_C + cg);
            op[0] = o0; op[1] = o1;
        }
    }
}

// ---- layer-2 aggregate: 32 lanes per node (2 nodes/wave), CSR pull, 8/2/1 unroll ----
__global__ void agg2_kernel(const int* __restrict__ row_ptr, const int* __restrict__ col,
                            const float* __restrict__ gs, const float* __restrict__ dinv,
                            const float* __restrict__ b2, float* __restrict__ out) {
    const int node = blockIdx.x * 8 + (threadIdx.x >> 5);
    const int c = threadIdx.x & 31;
    if (node >= N_NODES) return;
    const int beg = row_ptr[node], end = row_ptr[node + 1];
    float acc = gs[node * OUT_C + c];     // self loop
    int j = beg;
    for (; j + 7 < end; j += 8) {
        int s0 = col[j],     s1 = col[j + 1], s2 = col[j + 2], s3 = col[j + 3];
        int s4 = col[j + 4], s5 = col[j + 5], s6 = col[j + 6], s7 = col[j + 7];
        float v0 = gs[s0 * OUT_C + c], v1 = gs[s1 * OUT_C + c];
        float v2 = gs[s2 * OUT_C + c], v3 = gs[s3 * OUT_C + c];
        float v4 = gs[s4 * OUT_C + c], v5 = gs[s5 * OUT_C + c];
        float v6 = gs[s6 * OUT_C + c], v7 = gs[s7 * OUT_C + c];
        acc += ((v0 + v1) + (v2 + v3)) + ((v4 + v5) + (v6 + v7));
    }
    for (; j + 1 < end; j += 2) {
        int s0 = col[j], s1 = col[j + 1];
        float v0 = gs[s0 * OUT_C + c], v1 = gs[s1 * OUT_C + c];
        acc += v0 + v1;
    }
    if (j < end) acc += gs[col[j] * OUT_C + c];
    out[node * OUT_C + c] = dinv[node] * acc + b2[c];
}

extern "C" void kernel_launch(void* const* d_in, const int* in_sizes, int n_in,
                              void* d_out, int out_size, void* d_ws, size_t ws_size,
                              hipStream_t stream) {
    const float* x  = (const float*)d_in[0];   // [N,128]
    const int*   ei = (const int*)d_in[1];     // [2,E]
    const float* W1 = (const float*)d_in[2];   // [128,64]
    const float* b1 = (const float*)d_in[3];   // [64]
    const float* W2 = (const float*)d_in[4];   // [64,32]
    const float* b2 = (const float*)d_in[5];   // [32]
    float* out = (float*)d_out;                // [N,32]

    const int* srcv = ei;
    const int* dstv = ei + E_EDGES;

    // workspace layout (~58.5 MB)
    float* dinv = (float*)d_ws;                          // N
    float* hs   = dinv + N_NODES;                        // N*64 (reused as gs)
    float* h2   = hs + (size_t)N_NODES * HID_C;          // N*64
    int* bcnt      = (int*)(h2 + (size_t)N_NODES * HID_C); // NBUCK (counts -> cursor)
    int* boffs     = bcnt + NBUCK;                       // NBUCK+1
    int* row_ptr   = boffs + NBUCK + 1;                  // N+1
    unsigned* pairs = (unsigned*)(row_ptr + N_NODES + 1); // E (pairs -> sorted src = col)
    float* gs = hs;
    int* col = (int*)pairs;

    hipMemsetAsync(bcnt, 0, NBUCK * sizeof(int), stream);

    // CSR build via 64-node buckets + per-bucket counting sort
    bucket_count_kernel<<<(E_EDGES + 255) / 256, 256, 0, stream>>>(dstv, bcnt);
    bucket_scan_kernel<<<1, 1024, 0, stream>>>(bcnt, boffs);
    bucket_fill_kernel<<<(E_EDGES + 255) / 256, 256, 0, stream>>>(srcv, dstv, bcnt, pairs);
    bucket_sort_kernel<<<NBUCK, 256, 0, stream>>>(boffs, pairs, row_ptr, dinv);

    // layer 1
    gemm1_kernel<<<(N_NODES + 127) / 128, 256, 0, stream>>>(x, W1, dinv, hs);
    agg1_kernel<<<(N_NODES + 3) / 4, 256, 0, stream>>>(row_ptr, col, hs, dinv, b1, h2);

    // layer 2
    gemm2_kernel<<<(N_NODES + 127) / 128, 256, 0, stream>>>(h2, W2, dinv, gs);
    agg2_kernel<<<(N_NODES + 7) / 8, 256, 0, stream>>>(row_ptr, col, gs, dinv, b2, out);
}

// Round 6
// 299.866 us; speedup vs baseline: 5.2076x; 2.4225x over previous
//
#include <hip/hip_runtime.h>

#define N_NODES 100000
#define E_EDGES 1600000
#define IN_C 128
#define HID_C 64
#define OUT_C 32
#define BNODES 64                                   // nodes per bucket (dst>>6)
#define NBUCK ((N_NODES + BNODES - 1) / BNODES)     // 1563
#define MAXB 2048                                   // bucket cap (mean 1024, sigma~32)
#define NCHUNK 128                                  // edge chunks (privatized sort)
#define CHUNK_E (E_EDGES / NCHUNK)                  // 12500
#define SCAN_N (NBUCK * NCHUNK)                     // 200064 counts to scan
#define SCAN_NB ((SCAN_N + 255) / 256)              // 782 blocks <= 1024

// ---- chunk histogram: block k histograms its 12.5k-edge slice in LDS (no global atomics),
//      writes hist[bucket*NCHUNK + k] ----
__global__ __launch_bounds__(256) void chunk_hist_kernel(const int* __restrict__ dst,
                                                         int* __restrict__ hist) {
    __shared__ int h[NBUCK];
    for (int i = threadIdx.x; i < NBUCK; i += 256) h[i] = 0;
    __syncthreads();
    const int base = blockIdx.x * CHUNK_E;
    for (int j = threadIdx.x; j < CHUNK_E; j += 256)
        atomicAdd(&h[dst[base + j] >> 6], 1);
    __syncthreads();
    for (int i = threadIdx.x; i < NBUCK; i += 256)
        hist[i * NCHUNK + blockIdx.x] = h[i];
}

// ---- 3-stage exclusive scan over hist[SCAN_N] (bucket-major) ----
__global__ void scan1_kernel(int* __restrict__ data, int* __restrict__ bsums) {
    __shared__ int s[256];
    int i = blockIdx.x * 256 + threadIdx.x;
    int v = (i < SCAN_N) ? data[i] : 0;
    s[threadIdx.x] = v;
    __syncthreads();
    for (int off = 1; off < 256; off <<= 1) {
        int t = (threadIdx.x >= off) ? s[threadIdx.x - off] : 0;
        __syncthreads();
        s[threadIdx.x] += t;
        __syncthreads();
    }
    if (i < SCAN_N) data[i] = s[threadIdx.x] - v;   // exclusive within block
    if (threadIdx.x == 255) bsums[blockIdx.x] = s[255];
}

__global__ __launch_bounds__(1024) void scan2_kernel(int* __restrict__ bsums) {
    __shared__ int s[1024];
    int v = (threadIdx.x < SCAN_NB) ? bsums[threadIdx.x] : 0;
    s[threadIdx.x] = v;
    __syncthreads();
    for (int off = 1; off < 1024; off <<= 1) {
        int t = (threadIdx.x >= off) ? s[threadIdx.x - off] : 0;
        __syncthreads();
        s[threadIdx.x] += t;
        __syncthreads();
    }
    if (threadIdx.x < SCAN_NB) bsums[threadIdx.x] = s[threadIdx.x] - v;
}

__global__ void scan3_kernel(int* __restrict__ data, const int* __restrict__ bsums) {
    int i = blockIdx.x * 256 + threadIdx.x;
    if (i < SCAN_N) data[i] += bsums[blockIdx.x];
}

// ---- chunk fill: block k re-reads its slice, scatters into its PRIVATE windows.
//      Cursors in LDS; no global atomics, no cross-XCD cursor lines. ----
__global__ __launch_bounds__(256) void chunk_fill_kernel(const int* __restrict__ src,
                                                         const int* __restrict__ dst,
                                                         const int* __restrict__ hist,
                                                         unsigned* __restrict__ pairs) {
    __shared__ int cur[NBUCK];
    for (int i = threadIdx.x; i < NBUCK; i += 256)
        cur[i] = hist[i * NCHUNK + blockIdx.x];
    __syncthreads();
    const int base = blockIdx.x * CHUNK_E;
    for (int j = threadIdx.x; j < CHUNK_E; j += 256) {
        int d = dst[base + j];
        int pos = atomicAdd(&cur[d >> 6], 1);
        pairs[pos] = ((unsigned)src[base + j] << 6) | (unsigned)(d & 63);
    }
}

// ---- per-bucket counting sort -> node-level CSR, in place (LDS stage).
//      Writes row_ptr, dinv; pairs[beg..end) becomes src sorted by dst node. ----
__global__ __launch_bounds__(256) void bucket_sort_kernel(const int* __restrict__ hist,
                                                          unsigned* __restrict__ pairs,
                                                          int* __restrict__ row_ptr,
                                                          float* __restrict__ dinv) {
    __shared__ unsigned sp[MAXB];
    __shared__ int hcnt[BNODES], scn[BNODES], cur[BNODES];
    const int b = blockIdx.x;
    const int beg = hist[b * NCHUNK];
    const int end = (b + 1 < NBUCK) ? hist[(b + 1) * NCHUNK] : E_EDGES;
    const int cnt = end - beg;
    if (threadIdx.x < BNODES) hcnt[threadIdx.x] = 0;
    __syncthreads();
    for (int j = threadIdx.x; j < cnt; j += 256) {
        unsigned p = pairs[beg + j];
        sp[j] = p;
        atomicAdd(&hcnt[p & 63], 1);
    }
    __syncthreads();
    if (threadIdx.x < BNODES) scn[threadIdx.x] = hcnt[threadIdx.x];
    __syncthreads();
    for (int off = 1; off < BNODES; off <<= 1) {
        int t = 0;
        if (threadIdx.x < BNODES && threadIdx.x >= off) t = scn[threadIdx.x - off];
        __syncthreads();
        if (threadIdx.x < BNODES) scn[threadIdx.x] += t;
        __syncthreads();
    }
    if (threadIdx.x < BNODES) {
        int ex = scn[threadIdx.x] - hcnt[threadIdx.x];   // exclusive
        cur[threadIdx.x] = ex;
        int node = b * BNODES + threadIdx.x;
        if (node < N_NODES) {
            row_ptr[node] = beg + ex;
            dinv[node] = rsqrtf((float)hcnt[threadIdx.x] + 1.0f);
        }
    }
    if (threadIdx.x == 0 && b == NBUCK - 1) row_ptr[N_NODES] = E_EDGES;
    __syncthreads();
    for (int j = threadIdx.x; j < cnt; j += 256) {
        unsigned p = sp[j];
        int pos = atomicAdd(&cur[p & 63], 1);
        pairs[beg + pos] = p >> 6;                      // now plain src index
    }
}

// ---- hs = dinv[row] * (x @ W1) : register-tiled 4 rows x 8 cols per thread ----
__global__ __launch_bounds__(256) void gemm1_kernel(const float* __restrict__ x,
                                                    const float* __restrict__ W1,
                                                    const float* __restrict__ dinv,
                                                    float* __restrict__ hs) {
    __shared__ float sW[IN_C * HID_C];
    for (int i = threadIdx.x; i < IN_C * HID_C; i += 256) sW[i] = W1[i];
    __syncthreads();
    const int cg = (threadIdx.x & 7) * 8;
    const int row0 = blockIdx.x * 128 + (threadIdx.x >> 3) * 4;
    float acc[4][8];
#pragma unroll
    for (int r = 0; r < 4; ++r)
#pragma unroll
        for (int c = 0; c < 8; ++c) acc[r][c] = 0.f;

    int rr[4];
#pragma unroll
    for (int r = 0; r < 4; ++r) rr[r] = min(row0 + r, N_NODES - 1);

    const float4* x4 = (const float4*)x;
#pragma unroll 2
    for (int k4 = 0; k4 < IN_C / 4; ++k4) {
        float4 xv[4];
#pragma unroll
        for (int r = 0; r < 4; ++r) xv[r] = x4[(size_t)rr[r] * (IN_C / 4) + k4];
        float xs[4][4];
#pragma unroll
        for (int r = 0; r < 4; ++r) {
            xs[r][0] = xv[r].x; xs[r][1] = xv[r].y; xs[r][2] = xv[r].z; xs[r][3] = xv[r].w;
        }
#pragma unroll
        for (int kk = 0; kk < 4; ++kk) {
            const float4* wp = (const float4*)(sW + (k4 * 4 + kk) * HID_C + cg);
            float4 w0 = wp[0], w1 = wp[1];
            float wv[8] = {w0.x, w0.y, w0.z, w0.w, w1.x, w1.y, w1.z, w1.w};
#pragma unroll
            for (int r = 0; r < 4; ++r)
#pragma unroll
                for (int c = 0; c < 8; ++c)
                    acc[r][c] = fmaf(xs[r][kk], wv[c], acc[r][c]);
        }
    }
#pragma unroll
    for (int r = 0; r < 4; ++r) {
        int row = row0 + r;
        if (row < N_NODES) {
            float dv = dinv[row];
            float4 o0, o1;
            o0.x = acc[r][0] * dv; o0.y = acc[r][1] * dv; o0.z = acc[r][2] * dv; o0.w = acc[r][3] * dv;
            o1.x = acc[r][4] * dv; o1.y = acc[r][5] * dv; o1.z = acc[r][6] * dv; o1.w = acc[r][7] * dv;
            float4* op = (float4*)(hs + (size_t)row * HID_C + cg);
            op[0] = o0; op[1] = o1;
        }
    }
}

// ---- layer-1 aggregate: one wave per node (64 ch lanes), CSR pull, 8/2/1 unroll ----
__global__ void agg1_kernel(const int* __restrict__ row_ptr, const int* __restrict__ col,
                            const float* __restrict__ hs, const float* __restrict__ dinv,
                            const float* __restrict__ b1, float* __restrict__ h2) {
    const int node = blockIdx.x * 4 + (threadIdx.x >> 6);
    const int c = threadIdx.x & 63;
    if (node >= N_NODES) return;
    const int beg = row_ptr[node], end = row_ptr[node + 1];
    float acc = hs[node * HID_C + c];     // self loop
    int j = beg;
    for (; j + 7 < end; j += 8) {         // 8 independent gathers in flight
        int s0 = col[j],     s1 = col[j + 1], s2 = col[j + 2], s3 = col[j + 3];
        int s4 = col[j + 4], s5 = col[j + 5], s6 = col[j + 6], s7 = col[j + 7];
        float v0 = hs[s0 * HID_C + c], v1 = hs[s1 * HID_C + c];
        float v2 = hs[s2 * HID_C + c], v3 = hs[s3 * HID_C + c];
        float v4 = hs[s4 * HID_C + c], v5 = hs[s5 * HID_C + c];
        float v6 = hs[s6 * HID_C + c], v7 = hs[s7 * HID_C + c];
        acc += ((v0 + v1) + (v2 + v3)) + ((v4 + v5) + (v6 + v7));
    }
    for (; j + 1 < end; j += 2) {
        int s0 = col[j], s1 = col[j + 1];
        float v0 = hs[s0 * HID_C + c], v1 = hs[s1 * HID_C + c];
        acc += v0 + v1;
    }
    if (j < end) acc += hs[col[j] * HID_C + c];
    float v = dinv[node] * acc + b1[c];
    h2[node * HID_C + c] = fmaxf(v, 0.f);
}

// ---- gs = dinv[row] * (h2 @ W2) : register-tiled 2 rows x 8 cols per thread ----
__global__ __launch_bounds__(256) void gemm2_kernel(const float* __restrict__ h2,
                                                    const float* __restrict__ W2,
                                                    const float* __restrict__ dinv,
                                                    float* __restrict__ gs) {
    __shared__ float sW[HID_C * OUT_C];
    for (int i = threadIdx.x; i < HID_C * OUT_C; i += 256) sW[i] = W2[i];
    __syncthreads();
    const int cg = (threadIdx.x & 3) * 8;
    const int row0 = blockIdx.x * 128 + (threadIdx.x >> 2) * 2;
    float acc[2][8];
#pragma unroll
    for (int r = 0; r < 2; ++r)
#pragma unroll
        for (int c = 0; c < 8; ++c) acc[r][c] = 0.f;

    int rr[2];
#pragma unroll
    for (int r = 0; r < 2; ++r) rr[r] = min(row0 + r, N_NODES - 1);

    const float4* h4 = (const float4*)h2;
#pragma unroll 2
    for (int k4 = 0; k4 < HID_C / 4; ++k4) {
        float4 xv[2];
#pragma unroll
        for (int r = 0; r < 2; ++r) xv[r] = h4[(size_t)rr[r] * (HID_C / 4) + k4];
        float xs[2][4];
#pragma unroll
        for (int r = 0; r < 2; ++r) {
            xs[r][0] = xv[r].x; xs[r][1] = xv[r].y; xs[r][2] = xv[r].z; xs[r][3] = xv[r].w;
        }
#pragma unroll
        for (int kk = 0; kk < 4; ++kk) {
            const float4* wp = (const float4*)(sW + (k4 * 4 + kk) * OUT_C + cg);
            float4 w0 = wp[0], w1 = wp[1];
            float wv[8] = {w0.x, w0.y, w0.z, w0.w, w1.x, w1.y, w1.z, w1.w};
#pragma unroll
            for (int r = 0; r < 2; ++r)
#pragma unroll
                for (int c = 0; c < 8; ++c)
                    acc[r][c] = fmaf(xs[r][kk], wv[c], acc[r][c]);
        }
    }
#pragma unroll
    for (int r = 0; r < 2; ++r) {
        int row = row0 + r;
        if (row < N_NODES) {
            float dv = dinv[row];
            float4 o0, o1;
            o0.x = acc[r][0] * dv; o0.y = acc[r][1] * dv; o0.z = acc[r][2] * dv; o0.w = acc[r][3] * dv;
            o1.x = acc[r][4] * dv; o1.y = acc[r][5] * dv; o1.z = acc[r][6] * dv; o1.w = acc[r][7] * dv;
            float4* op = (float4*)(gs + (size_t)row * OUT_C + cg);
            op[0] = o0; op[1] = o1;
        }
    }
}

// ---- layer-2 aggregate: 32 lanes per node (2 nodes/wave), CSR pull, 8/2/1 unroll ----
__global__ void agg2_kernel(const int* __restrict__ row_ptr, const int* __restrict__ col,
                            const float* __restrict__ gs, const float* __restrict__ dinv,
                            const float* __restrict__ b2, float* __restrict__ out) {
    const int node = blockIdx.x * 8 + (threadIdx.x >> 5);
    const int c = threadIdx.x & 31;
    if (node >= N_NODES) return;
    const int beg = row_ptr[node], end = row_ptr[node + 1];
    float acc = gs[node * OUT_C + c];     // self loop
    int j = beg;
    for (; j + 7 < end; j += 8) {
        int s0 = col[j],     s1 = col[j + 1], s2 = col[j + 2], s3 = col[j + 3];
        int s4 = col[j + 4], s5 = col[j + 5], s6 = col[j + 6], s7 = col[j + 7];
        float v0 = gs[s0 * OUT_C + c], v1 = gs[s1 * OUT_C + c];
        float v2 = gs[s2 * OUT_C + c], v3 = gs[s3 * OUT_C + c];
        float v4 = gs[s4 * OUT_C + c], v5 = gs[s5 * OUT_C + c];
        float v6 = gs[s6 * OUT_C + c], v7 = gs[s7 * OUT_C + c];
        acc += ((v0 + v1) + (v2 + v3)) + ((v4 + v5) + (v6 + v7));
    }
    for (; j + 1 < end; j += 2) {
        int s0 = col[j], s1 = col[j + 1];
        float v0 = gs[s0 * OUT_C + c], v1 = gs[s1 * OUT_C + c];
        acc += v0 + v1;
    }
    if (j < end) acc += gs[col[j] * OUT_C + c];
    out[node * OUT_C + c] = dinv[node] * acc + b2[c];
}

extern "C" void kernel_launch(void* const* d_in, const int* in_sizes, int n_in,
                              void* d_out, int out_size, void* d_ws, size_t ws_size,
                              hipStream_t stream) {
    const float* x  = (const float*)d_in[0];   // [N,128]
    const int*   ei = (const int*)d_in[1];     // [2,E]
    const float* W1 = (const float*)d_in[2];   // [128,64]
    const float* b1 = (const float*)d_in[3];   // [64]
    const float* W2 = (const float*)d_in[4];   // [64,32]
    const float* b2 = (const float*)d_in[5];   // [32]
    float* out = (float*)d_out;                // [N,32]

    const int* srcv = ei;
    const int* dstv = ei + E_EDGES;

    // workspace layout (~59.2 MB; round 2 used 59.6 MB successfully)
    float* dinv = (float*)d_ws;                            // N
    float* hs   = dinv + N_NODES;                          // N*64 (reused as gs)
    float* h2   = hs + (size_t)N_NODES * HID_C;            // N*64
    int* hist      = (int*)(h2 + (size_t)N_NODES * HID_C); // NBUCK*NCHUNK (counts -> scanned offsets)
    int* bsums     = hist + SCAN_N;                        // 1024
    int* row_ptr   = bsums + 1024;                         // N+1
    unsigned* pairs = (unsigned*)(row_ptr + N_NODES + 1);  // E (pairs -> sorted src = col)
    float* gs = hs;
    int* col = (int*)pairs;

    // CSR build: chunk-privatized counting sort (no contended global atomics)
    chunk_hist_kernel<<<NCHUNK, 256, 0, stream>>>(dstv, hist);
    scan1_kernel<<<SCAN_NB, 256, 0, stream>>>(hist, bsums);
    scan2_kernel<<<1, 1024, 0, stream>>>(bsums);
    scan3_kernel<<<SCAN_NB, 256, 0, stream>>>(hist, bsums);
    chunk_fill_kernel<<<NCHUNK, 256, 0, stream>>>(srcv, dstv, hist, pairs);
    bucket_sort_kernel<<<NBUCK, 256, 0, stream>>>(hist, pairs, row_ptr, dinv);

    // layer 1
    gemm1_kernel<<<(N_NODES + 127) / 128, 256, 0, stream>>>(x, W1, dinv, hs);
    agg1_kernel<<<(N_NODES + 3) / 4, 256, 0, stream>>>(row_ptr, col, hs, dinv, b1, h2);

    // layer 2
    gemm2_kernel<<<(N_NODES + 127) / 128, 256, 0, stream>>>(h2, W2, dinv, gs);
    agg2_kernel<<<(N_NODES + 7) / 8, 256, 0, stream>>>(row_ptr, col, gs, dinv, b2, out);
}

// Round 7
// 263.421 us; speedup vs baseline: 5.9281x; 1.1384x over previous
//
#include <hip/hip_runtime.h>
#include <hip/hip_fp16.h>

#define N_NODES 100000
#define E_EDGES 1600000
#define IN_C 128
#define HID_C 64
#define OUT_C 32
#define BNODES 64                                   // nodes per bucket (dst>>6)
#define NBUCK ((N_NODES + BNODES - 1) / BNODES)     // 1563
#define MAXB 2048                                   // bucket cap (mean 1024, sigma~32)
#define NCHUNK 128                                  // edge chunks (privatized sort)
#define CHUNK_E (E_EDGES / NCHUNK)                  // 12500
#define SCAN_N (NBUCK * NCHUNK)                     // 200064 counts to scan
#define SCAN_NB ((SCAN_N + 255) / 256)              // 782 blocks <= 1024

// ---- chunk histogram: block k histograms its 12.5k-edge slice in LDS ----
__global__ __launch_bounds__(256) void chunk_hist_kernel(const int* __restrict__ dst,
                                                         int* __restrict__ hist) {
    __shared__ int h[NBUCK];
    for (int i = threadIdx.x; i < NBUCK; i += 256) h[i] = 0;
    __syncthreads();
    const int base = blockIdx.x * CHUNK_E;
    for (int j = threadIdx.x; j < CHUNK_E; j += 256)
        atomicAdd(&h[dst[base + j] >> 6], 1);
    __syncthreads();
    for (int i = threadIdx.x; i < NBUCK; i += 256)
        hist[i * NCHUNK + blockIdx.x] = h[i];
}

// ---- 3-stage exclusive scan over hist[SCAN_N] (bucket-major) ----
__global__ void scan1_kernel(int* __restrict__ data, int* __restrict__ bsums) {
    __shared__ int s[256];
    int i = blockIdx.x * 256 + threadIdx.x;
    int v = (i < SCAN_N) ? data[i] : 0;
    s[threadIdx.x] = v;
    __syncthreads();
    for (int off = 1; off < 256; off <<= 1) {
        int t = (threadIdx.x >= off) ? s[threadIdx.x - off] : 0;
        __syncthreads();
        s[threadIdx.x] += t;
        __syncthreads();
    }
    if (i < SCAN_N) data[i] = s[threadIdx.x] - v;   // exclusive within block
    if (threadIdx.x == 255) bsums[blockIdx.x] = s[255];
}

__global__ __launch_bounds__(1024) void scan2_kernel(int* __restrict__ bsums) {
    __shared__ int s[1024];
    int v = (threadIdx.x < SCAN_NB) ? bsums[threadIdx.x] : 0;
    s[threadIdx.x] = v;
    __syncthreads();
    for (int off = 1; off < 1024; off <<= 1) {
        int t = (threadIdx.x >= off) ? s[threadIdx.x - off] : 0;
        __syncthreads();
        s[threadIdx.x] += t;
        __syncthreads();
    }
    if (threadIdx.x < SCAN_NB) bsums[threadIdx.x] = s[threadIdx.x] - v;
}

__global__ void scan3_kernel(int* __restrict__ data, const int* __restrict__ bsums) {
    int i = blockIdx.x * 256 + threadIdx.x;
    if (i < SCAN_N) data[i] += bsums[blockIdx.x];
}

// ---- chunk fill: block k scatters its slice into PRIVATE windows (LDS cursors) ----
__global__ __launch_bounds__(256) void chunk_fill_kernel(const int* __restrict__ src,
                                                         const int* __restrict__ dst,
                                                         const int* __restrict__ hist,
                                                         unsigned* __restrict__ pairs) {
    __shared__ int cur[NBUCK];
    for (int i = threadIdx.x; i < NBUCK; i += 256)
        cur[i] = hist[i * NCHUNK + blockIdx.x];
    __syncthreads();
    const int base = blockIdx.x * CHUNK_E;
    for (int j = threadIdx.x; j < CHUNK_E; j += 256) {
        int d = dst[base + j];
        int pos = atomicAdd(&cur[d >> 6], 1);
        pairs[pos] = ((unsigned)src[base + j] << 6) | (unsigned)(d & 63);
    }
}

// ---- per-bucket counting sort -> node-level CSR, in place (LDS stage) ----
__global__ __launch_bounds__(256) void bucket_sort_kernel(const int* __restrict__ hist,
                                                          unsigned* __restrict__ pairs,
                                                          int* __restrict__ row_ptr,
                                                          float* __restrict__ dinv) {
    __shared__ unsigned sp[MAXB];
    __shared__ int hcnt[BNODES], scn[BNODES], cur[BNODES];
    const int b = blockIdx.x;
    const int beg = hist[b * NCHUNK];
    const int end = (b + 1 < NBUCK) ? hist[(b + 1) * NCHUNK] : E_EDGES;
    const int cnt = end - beg;
    if (threadIdx.x < BNODES) hcnt[threadIdx.x] = 0;
    __syncthreads();
    for (int j = threadIdx.x; j < cnt; j += 256) {
        unsigned p = pairs[beg + j];
        sp[j] = p;
        atomicAdd(&hcnt[p & 63], 1);
    }
    __syncthreads();
    if (threadIdx.x < BNODES) scn[threadIdx.x] = hcnt[threadIdx.x];
    __syncthreads();
    for (int off = 1; off < BNODES; off <<= 1) {
        int t = 0;
        if (threadIdx.x < BNODES && threadIdx.x >= off) t = scn[threadIdx.x - off];
        __syncthreads();
        if (threadIdx.x < BNODES) scn[threadIdx.x] += t;
        __syncthreads();
    }
    if (threadIdx.x < BNODES) {
        int ex = scn[threadIdx.x] - hcnt[threadIdx.x];   // exclusive
        cur[threadIdx.x] = ex;
        int node = b * BNODES + threadIdx.x;
        if (node < N_NODES) {
            row_ptr[node] = beg + ex;
            dinv[node] = rsqrtf((float)hcnt[threadIdx.x] + 1.0f);
        }
    }
    if (threadIdx.x == 0 && b == NBUCK - 1) row_ptr[N_NODES] = E_EDGES;
    __syncthreads();
    for (int j = threadIdx.x; j < cnt; j += 256) {
        unsigned p = sp[j];
        int pos = atomicAdd(&cur[p & 63], 1);
        pairs[beg + pos] = p >> 6;                      // now plain src index
    }
}

// ---- hs(fp16) = dinv[row] * (x @ W1) : register-tiled 4 rows x 8 cols per thread ----
__global__ __launch_bounds__(256) void gemm1_kernel(const float* __restrict__ x,
                                                    const float* __restrict__ W1,
                                                    const float* __restrict__ dinv,
                                                    __half* __restrict__ hs) {
    __shared__ float sW[IN_C * HID_C];
    for (int i = threadIdx.x; i < IN_C * HID_C; i += 256) sW[i] = W1[i];
    __syncthreads();
    const int cg = (threadIdx.x & 7) * 8;
    const int row0 = blockIdx.x * 128 + (threadIdx.x >> 3) * 4;
    float acc[4][8];
#pragma unroll
    for (int r = 0; r < 4; ++r)
#pragma unroll
        for (int c = 0; c < 8; ++c) acc[r][c] = 0.f;

    int rr[4];
#pragma unroll
    for (int r = 0; r < 4; ++r) rr[r] = min(row0 + r, N_NODES - 1);

    const float4* x4 = (const float4*)x;
#pragma unroll 2
    for (int k4 = 0; k4 < IN_C / 4; ++k4) {
        float4 xv[4];
#pragma unroll
        for (int r = 0; r < 4; ++r) xv[r] = x4[(size_t)rr[r] * (IN_C / 4) + k4];
        float xs[4][4];
#pragma unroll
        for (int r = 0; r < 4; ++r) {
            xs[r][0] = xv[r].x; xs[r][1] = xv[r].y; xs[r][2] = xv[r].z; xs[r][3] = xv[r].w;
        }
#pragma unroll
        for (int kk = 0; kk < 4; ++kk) {
            const float4* wp = (const float4*)(sW + (k4 * 4 + kk) * HID_C + cg);
            float4 w0 = wp[0], w1 = wp[1];
            float wv[8] = {w0.x, w0.y, w0.z, w0.w, w1.x, w1.y, w1.z, w1.w};
#pragma unroll
            for (int r = 0; r < 4; ++r)
#pragma unroll
                for (int c = 0; c < 8; ++c)
                    acc[r][c] = fmaf(xs[r][kk], wv[c], acc[r][c]);
        }
    }
#pragma unroll
    for (int r = 0; r < 4; ++r) {
        int row = row0 + r;
        if (row < N_NODES) {
            float dv = dinv[row];
            union { float4 f; __half2 h[4]; } u;
#pragma unroll
            for (int q = 0; q < 4; ++q)
                u.h[q] = __floats2half2_rn(acc[r][2 * q] * dv, acc[r][2 * q + 1] * dv);
            *(float4*)(hs + (size_t)row * HID_C + cg) = u.f;   // 16 B packed store
        }
    }
}

// ---- layer-1 aggregate: 32 lanes x half2 per node (2 nodes/wave), CSR pull, fp16 gather ----
__global__ void agg1_kernel(const int* __restrict__ row_ptr, const int* __restrict__ col,
                            const __half2* __restrict__ hs2, const float* __restrict__ dinv,
                            const float* __restrict__ b1, float* __restrict__ h2) {
    const int node = blockIdx.x * 8 + (threadIdx.x >> 5);
    const int c2 = threadIdx.x & 31;               // half2 index: channels 2*c2, 2*c2+1
    if (node >= N_NODES) return;
    const int beg = row_ptr[node], end = row_ptr[node + 1];
    float2 f = __half22float2(hs2[node * 32 + c2]);   // self loop
    float ax = f.x, ay = f.y;
    int j = beg;
    for (; j + 7 < end; j += 8) {                  // 8 independent gathers in flight
        int s0 = col[j],     s1 = col[j + 1], s2 = col[j + 2], s3 = col[j + 3];
        int s4 = col[j + 4], s5 = col[j + 5], s6 = col[j + 6], s7 = col[j + 7];
        float2 v0 = __half22float2(hs2[s0 * 32 + c2]);
        float2 v1 = __half22float2(hs2[s1 * 32 + c2]);
        float2 v2 = __half22float2(hs2[s2 * 32 + c2]);
        float2 v3 = __half22float2(hs2[s3 * 32 + c2]);
        float2 v4 = __half22float2(hs2[s4 * 32 + c2]);
        float2 v5 = __half22float2(hs2[s5 * 32 + c2]);
        float2 v6 = __half22float2(hs2[s6 * 32 + c2]);
        float2 v7 = __half22float2(hs2[s7 * 32 + c2]);
        ax += ((v0.x + v1.x) + (v2.x + v3.x)) + ((v4.x + v5.x) + (v6.x + v7.x));
        ay += ((v0.y + v1.y) + (v2.y + v3.y)) + ((v4.y + v5.y) + (v6.y + v7.y));
    }
    for (; j + 1 < end; j += 2) {
        int s0 = col[j], s1 = col[j + 1];
        float2 v0 = __half22float2(hs2[s0 * 32 + c2]);
        float2 v1 = __half22float2(hs2[s1 * 32 + c2]);
        ax += v0.x + v1.x; ay += v0.y + v1.y;
    }
    if (j < end) {
        float2 v = __half22float2(hs2[col[j] * 32 + c2]);
        ax += v.x; ay += v.y;
    }
    float dv = dinv[node];
    float2 bb = ((const float2*)b1)[c2];
    float2 o;
    o.x = fmaxf(dv * ax + bb.x, 0.f);
    o.y = fmaxf(dv * ay + bb.y, 0.f);
    ((float2*)h2)[node * 32 + c2] = o;
}

// ---- gs(fp16) = dinv[row] * (h2 @ W2) : register-tiled 2 rows x 8 cols per thread ----
__global__ __launch_bounds__(256) void gemm2_kernel(const float* __restrict__ h2,
                                                    const float* __restrict__ W2,
                                                    const float* __restrict__ dinv,
                                                    __half* __restrict__ gs) {
    __shared__ float sW[HID_C * OUT_C];
    for (int i = threadIdx.x; i < HID_C * OUT_C; i += 256) sW[i] = W2[i];
    __syncthreads();
    const int cg = (threadIdx.x & 3) * 8;
    const int row0 = blockIdx.x * 128 + (threadIdx.x >> 2) * 2;
    float acc[2][8];
#pragma unroll
    for (int r = 0; r < 2; ++r)
#pragma unroll
        for (int c = 0; c < 8; ++c) acc[r][c] = 0.f;

    int rr[2];
#pragma unroll
    for (int r = 0; r < 2; ++r) rr[r] = min(row0 + r, N_NODES - 1);

    const float4* h4 = (const float4*)h2;
#pragma unroll 2
    for (int k4 = 0; k4 < HID_C / 4; ++k4) {
        float4 xv[2];
#pragma unroll
        for (int r = 0; r < 2; ++r) xv[r] = h4[(size_t)rr[r] * (HID_C / 4) + k4];
        float xs[2][4];
#pragma unroll
        for (int r = 0; r < 2; ++r) {
            xs[r][0] = xv[r].x; xs[r][1] = xv[r].y; xs[r][2] = xv[r].z; xs[r][3] = xv[r].w;
        }
#pragma unroll
        for (int kk = 0; kk < 4; ++kk) {
            const float4* wp = (const float4*)(sW + (k4 * 4 + kk) * OUT_C + cg);
            float4 w0 = wp[0], w1 = wp[1];
            float wv[8] = {w0.x, w0.y, w0.z, w0.w, w1.x, w1.y, w1.z, w1.w};
#pragma unroll
            for (int r = 0; r < 2; ++r)
#pragma unroll
                for (int c = 0; c < 8; ++c)
                    acc[r][c] = fmaf(xs[r][kk], wv[c], acc[r][c]);
        }
    }
#pragma unroll
    for (int r = 0; r < 2; ++r) {
        int row = row0 + r;
        if (row < N_NODES) {
            float dv = dinv[row];
            union { float4 f; __half2 h[4]; } u;
#pragma unroll
            for (int q = 0; q < 4; ++q)
                u.h[q] = __floats2half2_rn(acc[r][2 * q] * dv, acc[r][2 * q + 1] * dv);
            *(float4*)(gs + (size_t)row * OUT_C + cg) = u.f;
        }
    }
}

// ---- layer-2 aggregate: 16 lanes x half2 per node (4 nodes/wave), CSR pull, fp16 gather ----
__global__ void agg2_kernel(const int* __restrict__ row_ptr, const int* __restrict__ col,
                            const __half2* __restrict__ gs2, const float* __restrict__ dinv,
                            const float* __restrict__ b2, float* __restrict__ out) {
    const int node = blockIdx.x * 16 + (threadIdx.x >> 4);
    const int c2 = threadIdx.x & 15;               // half2 index: channels 2*c2, 2*c2+1
    if (node >= N_NODES) return;
    const int beg = row_ptr[node], end = row_ptr[node + 1];
    float2 f = __half22float2(gs2[node * 16 + c2]);   // self loop
    float ax = f.x, ay = f.y;
    int j = beg;
    for (; j + 7 < end; j += 8) {
        int s0 = col[j],     s1 = col[j + 1], s2 = col[j + 2], s3 = col[j + 3];
        int s4 = col[j + 4], s5 = col[j + 5], s6 = col[j + 6], s7 = col[j + 7];
        float2 v0 = __half22float2(gs2[s0 * 16 + c2]);
        float2 v1 = __half22float2(gs2[s1 * 16 + c2]);
        float2 v2 = __half22float2(gs2[s2 * 16 + c2]);
        float2 v3 = __half22float2(gs2[s3 * 16 + c2]);
        float2 v4 = __half22float2(gs2[s4 * 16 + c2]);
        float2 v5 = __half22float2(gs2[s5 * 16 + c2]);
        float2 v6 = __half22float2(gs2[s6 * 16 + c2]);
        float2 v7 = __half22float2(gs2[s7 * 16 + c2]);
        ax += ((v0.x + v1.x) + (v2.x + v3.x)) + ((v4.x + v5.x) + (v6.x + v7.x));
        ay += ((v0.y + v1.y) + (v2.y + v3.y)) + ((v4.y + v5.y) + (v6.y + v7.y));
    }
    for (; j + 1 < end; j += 2) {
        int s0 = col[j], s1 = col[j + 1];
        float2 v0 = __half22float2(gs2[s0 * 16 + c2]);
        float2 v1 = __half22float2(gs2[s1 * 16 + c2]);
        ax += v0.x + v1.x; ay += v0.y + v1.y;
    }
    if (j < end) {
        float2 v = __half22float2(gs2[col[j] * 16 + c2]);
        ax += v.x; ay += v.y;
    }
    float dv = dinv[node];
    float2 bb = ((const float2*)b2)[c2];
    float2 o;
    o.x = dv * ax + bb.x;
    o.y = dv * ay + bb.y;
    ((float2*)out)[node * 16 + c2] = o;
}

extern "C" void kernel_launch(void* const* d_in, const int* in_sizes, int n_in,
                              void* d_out, int out_size, void* d_ws, size_t ws_size,
                              hipStream_t stream) {
    const float* x  = (const float*)d_in[0];   // [N,128]
    const int*   ei = (const int*)d_in[1];     // [2,E]
    const float* W1 = (const float*)d_in[2];   // [128,64]
    const float* b1 = (const float*)d_in[3];   // [64]
    const float* W2 = (const float*)d_in[4];   // [64,32]
    const float* b2 = (const float*)d_in[5];   // [32]
    float* out = (float*)d_out;                // [N,32]

    const int* srcv = ei;
    const int* dstv = ei + E_EDGES;

    // workspace layout (~46.4 MB)
    float* dinv = (float*)d_ws;                            // N floats
    __half* hs  = (__half*)(dinv + N_NODES);               // N*64 halves (reused as gs)
    float* h2   = (float*)(hs + (size_t)N_NODES * HID_C);  // N*64 floats
    int* hist      = (int*)(h2 + (size_t)N_NODES * HID_C); // NBUCK*NCHUNK
    int* bsums     = hist + SCAN_N;                        // 1024
    int* row_ptr   = bsums + 1024;                         // N+1
    unsigned* pairs = (unsigned*)(row_ptr + N_NODES + 1);  // E (pairs -> sorted src = col)
    __half* gs = hs;                                       // reuse after agg1
    int* col = (int*)pairs;

    // CSR build: chunk-privatized counting sort (no contended global atomics)
    chunk_hist_kernel<<<NCHUNK, 256, 0, stream>>>(dstv, hist);
    scan1_kernel<<<SCAN_NB, 256, 0, stream>>>(hist, bsums);
    scan2_kernel<<<1, 1024, 0, stream>>>(bsums);
    scan3_kernel<<<SCAN_NB, 256, 0, stream>>>(hist, bsums);
    chunk_fill_kernel<<<NCHUNK, 256, 0, stream>>>(srcv, dstv, hist, pairs);
    bucket_sort_kernel<<<NBUCK, 256, 0, stream>>>(hist, pairs, row_ptr, dinv);

    // layer 1
    gemm1_kernel<<<(N_NODES + 127) / 128, 256, 0, stream>>>(x, W1, dinv, hs);
    agg1_kernel<<<(N_NODES + 7) / 8, 256, 0, stream>>>(row_ptr, col, (const __half2*)hs,
                                                       dinv, b1, h2);

    // layer 2
    gemm2_kernel<<<(N_NODES + 127) / 128, 256, 0, stream>>>(h2, W2, dinv, gs);
    agg2_kernel<<<(N_NODES + 15) / 16, 256, 0, stream>>>(row_ptr, col, (const __half2*)gs,
                                                         dinv, b2, out);
}

// Round 8
// 233.193 us; speedup vs baseline: 6.6965x; 1.1296x over previous
//
#include <hip/hip_runtime.h>
#include <hip/hip_fp16.h>

#define N_NODES 100000
#define E_EDGES 1600000
#define IN_C 128
#define HID_C 64
#define OUT_C 32
#define BNODES 64                                   // nodes per bucket (dst>>6)
#define NBUCK ((N_NODES + BNODES - 1) / BNODES)     // 1563
#define MAXB 2048                                   // bucket cap (mean 1024, sigma~32)
#define NCHUNK 256                                  // edge chunks (privatized sort)
#define CHUNK_E (E_EDGES / NCHUNK)                  // 6250
#define SCAN_N (NBUCK * NCHUNK)                     // 400128 counts to scan
#define SCAN_NB (SCAN_N / 256)                      // 1563 blocks

// chunk<->block swizzle: consecutive chunks land on the same XCD (blockIdx%8 heuristic),
// so adjacent pairs-windows (shared 64B lines) merge in one L2 instead of ping-ponging.
__device__ __forceinline__ int chunk_of_block(int b) { return (b & 7) * (NCHUNK / 8) + (b >> 3); }

// ---- chunk histogram: block k histograms its 6250-edge slice in LDS (1024 thr) ----
__global__ __launch_bounds__(1024) void chunk_hist_kernel(const int* __restrict__ dst,
                                                          int* __restrict__ hist) {
    __shared__ int h[NBUCK];
    for (int i = threadIdx.x; i < NBUCK; i += 1024) h[i] = 0;
    __syncthreads();
    const int chunk = chunk_of_block(blockIdx.x);
    const int base = chunk * CHUNK_E;
    for (int j = threadIdx.x; j < CHUNK_E; j += 1024)
        atomicAdd(&h[dst[base + j] >> 6], 1);
    __syncthreads();
    for (int i = threadIdx.x; i < NBUCK; i += 1024)
        hist[i * NCHUNK + chunk] = h[i];
}

// ---- 3-stage exclusive scan over hist[SCAN_N] (bucket-major) ----
__global__ void scan1_kernel(int* __restrict__ data, int* __restrict__ bsums) {
    __shared__ int s[256];
    int i = blockIdx.x * 256 + threadIdx.x;
    int v = data[i];
    s[threadIdx.x] = v;
    __syncthreads();
    for (int off = 1; off < 256; off <<= 1) {
        int t = (threadIdx.x >= off) ? s[threadIdx.x - off] : 0;
        __syncthreads();
        s[threadIdx.x] += t;
        __syncthreads();
    }
    data[i] = s[threadIdx.x] - v;                   // exclusive within block
    if (threadIdx.x == 255) bsums[blockIdx.x] = s[255];
}

__global__ __launch_bounds__(1024) void scan2_kernel(int* __restrict__ bsums) {
    __shared__ int s[1024];
    int total = 0;
    for (int base = 0; base < SCAN_NB; base += 1024) {
        int i = base + threadIdx.x;
        int v = (i < SCAN_NB) ? bsums[i] : 0;
        s[threadIdx.x] = v;
        __syncthreads();
        for (int off = 1; off < 1024; off <<= 1) {
            int t = (threadIdx.x >= off) ? s[threadIdx.x - off] : 0;
            __syncthreads();
            s[threadIdx.x] += t;
            __syncthreads();
        }
        if (i < SCAN_NB) bsums[i] = total + s[threadIdx.x] - v;
        total += s[1023];
        __syncthreads();
    }
}

__global__ void scan3_kernel(int* __restrict__ data, const int* __restrict__ bsums) {
    int i = blockIdx.x * 256 + threadIdx.x;
    data[i] += bsums[blockIdx.x];
}

// ---- chunk fill: block k scatters its slice into PRIVATE windows (LDS cursors, 1024 thr) ----
__global__ __launch_bounds__(1024) void chunk_fill_kernel(const int* __restrict__ src,
                                                          const int* __restrict__ dst,
                                                          const int* __restrict__ hist,
                                                          unsigned* __restrict__ pairs) {
    __shared__ int cur[NBUCK];
    const int chunk = chunk_of_block(blockIdx.x);
    for (int i = threadIdx.x; i < NBUCK; i += 1024)
        cur[i] = hist[i * NCHUNK + chunk];
    __syncthreads();
    const int base = chunk * CHUNK_E;
    for (int j = threadIdx.x; j < CHUNK_E; j += 1024) {
        int d = dst[base + j];
        int pos = atomicAdd(&cur[d >> 6], 1);
        pairs[pos] = ((unsigned)src[base + j] << 6) | (unsigned)(d & 63);
    }
}

// ---- per-bucket counting sort -> node-level CSR, in place (LDS stage) ----
__global__ __launch_bounds__(256) void bucket_sort_kernel(const int* __restrict__ hist,
                                                          unsigned* __restrict__ pairs,
                                                          int* __restrict__ row_ptr,
                                                          float* __restrict__ dinv) {
    __shared__ unsigned sp[MAXB];
    __shared__ int hcnt[BNODES], scn[BNODES], cur[BNODES];
    const int b = blockIdx.x;
    const int beg = hist[b * NCHUNK];
    const int end = (b + 1 < NBUCK) ? hist[(b + 1) * NCHUNK] : E_EDGES;
    const int cnt = end - beg;
    if (threadIdx.x < BNODES) hcnt[threadIdx.x] = 0;
    __syncthreads();
    for (int j = threadIdx.x; j < cnt; j += 256) {
        unsigned p = pairs[beg + j];
        sp[j] = p;
        atomicAdd(&hcnt[p & 63], 1);
    }
    __syncthreads();
    if (threadIdx.x < BNODES) scn[threadIdx.x] = hcnt[threadIdx.x];
    __syncthreads();
    for (int off = 1; off < BNODES; off <<= 1) {
        int t = 0;
        if (threadIdx.x < BNODES && threadIdx.x >= off) t = scn[threadIdx.x - off];
        __syncthreads();
        if (threadIdx.x < BNODES) scn[threadIdx.x] += t;
        __syncthreads();
    }
    if (threadIdx.x < BNODES) {
        int ex = scn[threadIdx.x] - hcnt[threadIdx.x];   // exclusive
        cur[threadIdx.x] = ex;
        int node = b * BNODES + threadIdx.x;
        if (node < N_NODES) {
            row_ptr[node] = beg + ex;
            dinv[node] = rsqrtf((float)hcnt[threadIdx.x] + 1.0f);
        }
    }
    if (threadIdx.x == 0 && b == NBUCK - 1) row_ptr[N_NODES] = E_EDGES;
    __syncthreads();
    for (int j = threadIdx.x; j < cnt; j += 256) {
        unsigned p = sp[j];
        int pos = atomicAdd(&cur[p & 63], 1);
        pairs[beg + pos] = p >> 6;                      // now plain src index
    }
}

// ---- hs(fp16) = dinv[row] * (x @ W1) : register-tiled 4 rows x 8 cols per thread ----
__global__ __launch_bounds__(256) void gemm1_kernel(const float* __restrict__ x,
                                                    const float* __restrict__ W1,
                                                    const float* __restrict__ dinv,
                                                    __half* __restrict__ hs) {
    __shared__ float sW[IN_C * HID_C];
    for (int i = threadIdx.x; i < IN_C * HID_C; i += 256) sW[i] = W1[i];
    __syncthreads();
    const int cg = (threadIdx.x & 7) * 8;
    const int row0 = blockIdx.x * 128 + (threadIdx.x >> 3) * 4;
    float acc[4][8];
#pragma unroll
    for (int r = 0; r < 4; ++r)
#pragma unroll
        for (int c = 0; c < 8; ++c) acc[r][c] = 0.f;

    int rr[4];
#pragma unroll
    for (int r = 0; r < 4; ++r) rr[r] = min(row0 + r, N_NODES - 1);

    const float4* x4 = (const float4*)x;
#pragma unroll 2
    for (int k4 = 0; k4 < IN_C / 4; ++k4) {
        float4 xv[4];
#pragma unroll
        for (int r = 0; r < 4; ++r) xv[r] = x4[(size_t)rr[r] * (IN_C / 4) + k4];
        float xs[4][4];
#pragma unroll
        for (int r = 0; r < 4; ++r) {
            xs[r][0] = xv[r].x; xs[r][1] = xv[r].y; xs[r][2] = xv[r].z; xs[r][3] = xv[r].w;
        }
#pragma unroll
        for (int kk = 0; kk < 4; ++kk) {
            const float4* wp = (const float4*)(sW + (k4 * 4 + kk) * HID_C + cg);
            float4 w0 = wp[0], w1 = wp[1];
            float wv[8] = {w0.x, w0.y, w0.z, w0.w, w1.x, w1.y, w1.z, w1.w};
#pragma unroll
            for (int r = 0; r < 4; ++r)
#pragma unroll
                for (int c = 0; c < 8; ++c)
                    acc[r][c] = fmaf(xs[r][kk], wv[c], acc[r][c]);
        }
    }
#pragma unroll
    for (int r = 0; r < 4; ++r) {
        int row = row0 + r;
        if (row < N_NODES) {
            float dv = dinv[row];
            union { float4 f; __half2 h[4]; } u;
#pragma unroll
            for (int q = 0; q < 4; ++q)
                u.h[q] = __floats2half2_rn(acc[r][2 * q] * dv, acc[r][2 * q + 1] * dv);
            *(float4*)(hs + (size_t)row * HID_C + cg) = u.f;   // 16 B packed store
        }
    }
}

// ---- layer-1 aggregate: 32 lanes x half2 per node (2 nodes/wave), CSR pull, fp16 gather ----
__global__ void agg1_kernel(const int* __restrict__ row_ptr, const int* __restrict__ col,
                            const __half2* __restrict__ hs2, const float* __restrict__ dinv,
                            const float* __restrict__ b1, float* __restrict__ h2) {
    const int node = blockIdx.x * 8 + (threadIdx.x >> 5);
    const int c2 = threadIdx.x & 31;               // half2 index: channels 2*c2, 2*c2+1
    if (node >= N_NODES) return;
    const int beg = row_ptr[node], end = row_ptr[node + 1];
    float2 f = __half22float2(hs2[node * 32 + c2]);   // self loop
    float ax = f.x, ay = f.y;
    int j = beg;
    for (; j + 7 < end; j += 8) {                  // 8 independent gathers in flight
        int s0 = col[j],     s1 = col[j + 1], s2 = col[j + 2], s3 = col[j + 3];
        int s4 = col[j + 4], s5 = col[j + 5], s6 = col[j + 6], s7 = col[j + 7];
        float2 v0 = __half22float2(hs2[s0 * 32 + c2]);
        float2 v1 = __half22float2(hs2[s1 * 32 + c2]);
        float2 v2 = __half22float2(hs2[s2 * 32 + c2]);
        float2 v3 = __half22float2(hs2[s3 * 32 + c2]);
        float2 v4 = __half22float2(hs2[s4 * 32 + c2]);
        float2 v5 = __half22float2(hs2[s5 * 32 + c2]);
        float2 v6 = __half22float2(hs2[s6 * 32 + c2]);
        float2 v7 = __half22float2(hs2[s7 * 32 + c2]);
        ax += ((v0.x + v1.x) + (v2.x + v3.x)) + ((v4.x + v5.x) + (v6.x + v7.x));
        ay += ((v0.y + v1.y) + (v2.y + v3.y)) + ((v4.y + v5.y) + (v6.y + v7.y));
    }
    for (; j + 1 < end; j += 2) {
        int s0 = col[j], s1 = col[j + 1];
        float2 v0 = __half22float2(hs2[s0 * 32 + c2]);
        float2 v1 = __half22float2(hs2[s1 * 32 + c2]);
        ax += v0.x + v1.x; ay += v0.y + v1.y;
    }
    if (j < end) {
        float2 v = __half22float2(hs2[col[j] * 32 + c2]);
        ax += v.x; ay += v.y;
    }
    float dv = dinv[node];
    float2 bb = ((const float2*)b1)[c2];
    float2 o;
    o.x = fmaxf(dv * ax + bb.x, 0.f);
    o.y = fmaxf(dv * ay + bb.y, 0.f);
    ((float2*)h2)[node * 32 + c2] = o;
}

// ---- gs(fp16) = dinv[row] * (h2 @ W2) : register-tiled 2 rows x 8 cols per thread ----
__global__ __launch_bounds__(256) void gemm2_kernel(const float* __restrict__ h2,
                                                    const float* __restrict__ W2,
                                                    const float* __restrict__ dinv,
                                                    __half* __restrict__ gs) {
    __shared__ float sW[HID_C * OUT_C];
    for (int i = threadIdx.x; i < HID_C * OUT_C; i += 256) sW[i] = W2[i];
    __syncthreads();
    const int cg = (threadIdx.x & 3) * 8;
    const int row0 = blockIdx.x * 128 + (threadIdx.x >> 2) * 2;
    float acc[2][8];
#pragma unroll
    for (int r = 0; r < 2; ++r)
#pragma unroll
        for (int c = 0; c < 8; ++c) acc[r][c] = 0.f;

    int rr[2];
#pragma unroll
    for (int r = 0; r < 2; ++r) rr[r] = min(row0 + r, N_NODES - 1);

    const float4* h4 = (const float4*)h2;
#pragma unroll 2
    for (int k4 = 0; k4 < HID_C / 4; ++k4) {
        float4 xv[2];
#pragma unroll
        for (int r = 0; r < 2; ++r) xv[r] = h4[(size_t)rr[r] * (HID_C / 4) + k4];
        float xs[2][4];
#pragma unroll
        for (int r = 0; r < 2; ++r) {
            xs[r][0] = xv[r].x; xs[r][1] = xv[r].y; xs[r][2] = xv[r].z; xs[r][3] = xv[r].w;
        }
#pragma unroll
        for (int kk = 0; kk < 4; ++kk) {
            const float4* wp = (const float4*)(sW + (k4 * 4 + kk) * OUT_C + cg);
            float4 w0 = wp[0], w1 = wp[1];
            float wv[8] = {w0.x, w0.y, w0.z, w0.w, w1.x, w1.y, w1.z, w1.w};
#pragma unroll
            for (int r = 0; r < 2; ++r)
#pragma unroll
                for (int c = 0; c < 8; ++c)
                    acc[r][c] = fmaf(xs[r][kk], wv[c], acc[r][c]);
        }
    }
#pragma unroll
    for (int r = 0; r < 2; ++r) {
        int row = row0 + r;
        if (row < N_NODES) {
            float dv = dinv[row];
            union { float4 f; __half2 h[4]; } u;
#pragma unroll
            for (int q = 0; q < 4; ++q)
                u.h[q] = __floats2half2_rn(acc[r][2 * q] * dv, acc[r][2 * q + 1] * dv);
            *(float4*)(gs + (size_t)row * OUT_C + cg) = u.f;
        }
    }
}

// ---- layer-2 aggregate: 16 lanes x half2 per node (4 nodes/wave), CSR pull, fp16 gather ----
__global__ void agg2_kernel(const int* __restrict__ row_ptr, const int* __restrict__ col,
                            const __half2* __restrict__ gs2, const float* __restrict__ dinv,
                            const float* __restrict__ b2, float* __restrict__ out) {
    const int node = blockIdx.x * 16 + (threadIdx.x >> 4);
    const int c2 = threadIdx.x & 15;               // half2 index: channels 2*c2, 2*c2+1
    if (node >= N_NODES) return;
    const int beg = row_ptr[node], end = row_ptr[node + 1];
    float2 f = __half22float2(gs2[node * 16 + c2]);   // self loop
    float ax = f.x, ay = f.y;
    int j = beg;
    for (; j + 7 < end; j += 8) {
        int s0 = col[j],     s1 = col[j + 1], s2 = col[j + 2], s3 = col[j + 3];
        int s4 = col[j + 4], s5 = col[j + 5], s6 = col[j + 6], s7 = col[j + 7];
        float2 v0 = __half22float2(gs2[s0 * 16 + c2]);
        float2 v1 = __half22float2(gs2[s1 * 16 + c2]);
        float2 v2 = __half22float2(gs2[s2 * 16 + c2]);
        float2 v3 = __half22float2(gs2[s3 * 16 + c2]);
        float2 v4 = __half22float2(gs2[s4 * 16 + c2]);
        float2 v5 = __half22float2(gs2[s5 * 16 + c2]);
        float2 v6 = __half22float2(gs2[s6 * 16 + c2]);
        float2 v7 = __half22float2(gs2[s7 * 16 + c2]);
        ax += ((v0.x + v1.x) + (v2.x + v3.x)) + ((v4.x + v5.x) + (v6.x + v7.x));
        ay += ((v0.y + v1.y) + (v2.y + v3.y)) + ((v4.y + v5.y) + (v6.y + v7.y));
    }
    for (; j + 1 < end; j += 2) {
        int s0 = col[j], s1 = col[j + 1];
        float2 v0 = __half22float2(gs2[s0 * 16 + c2]);
        float2 v1 = __half22float2(gs2[s1 * 16 + c2]);
        ax += v0.x + v1.x; ay += v0.y + v1.y;
    }
    if (j < end) {
        float2 v = __half22float2(gs2[col[j] * 16 + c2]);
        ax += v.x; ay += v.y;
    }
    float dv = dinv[node];
    float2 bb = ((const float2*)b2)[c2];
    float2 o;
    o.x = dv * ax + bb.x;
    o.y = dv * ay + bb.y;
    ((float2*)out)[node * 16 + c2] = o;
}

extern "C" void kernel_launch(void* const* d_in, const int* in_sizes, int n_in,
                              void* d_out, int out_size, void* d_ws, size_t ws_size,
                              hipStream_t stream) {
    const float* x  = (const float*)d_in[0];   // [N,128]
    const int*   ei = (const int*)d_in[1];     // [2,E]
    const float* W1 = (const float*)d_in[2];   // [128,64]
    const float* b1 = (const float*)d_in[3];   // [64]
    const float* W2 = (const float*)d_in[4];   // [64,32]
    const float* b2 = (const float*)d_in[5];   // [32]
    float* out = (float*)d_out;                // [N,32]

    const int* srcv = ei;
    const int* dstv = ei + E_EDGES;

    // workspace layout (~47.2 MB)
    float* dinv = (float*)d_ws;                            // N floats
    __half* hs  = (__half*)(dinv + N_NODES);               // N*64 halves (reused as gs)
    float* h2   = (float*)(hs + (size_t)N_NODES * HID_C);  // N*64 floats
    int* hist      = (int*)(h2 + (size_t)N_NODES * HID_C); // NBUCK*NCHUNK (400k)
    int* bsums     = hist + SCAN_N;                        // SCAN_NB (1563)
    int* row_ptr   = bsums + SCAN_NB;                      // N+1
    unsigned* pairs = (unsigned*)(row_ptr + N_NODES + 1);  // E (pairs -> sorted src = col)
    __half* gs = hs;                                       // reuse after agg1
    int* col = (int*)pairs;

    // CSR build: chunk-privatized counting sort, full-occupancy distribution
    chunk_hist_kernel<<<NCHUNK, 1024, 0, stream>>>(dstv, hist);
    scan1_kernel<<<SCAN_NB, 256, 0, stream>>>(hist, bsums);
    scan2_kernel<<<1, 1024, 0, stream>>>(bsums);
    scan3_kernel<<<SCAN_NB, 256, 0, stream>>>(hist, bsums);
    chunk_fill_kernel<<<NCHUNK, 1024, 0, stream>>>(srcv, dstv, hist, pairs);
    bucket_sort_kernel<<<NBUCK, 256, 0, stream>>>(hist, pairs, row_ptr, dinv);

    // layer 1
    gemm1_kernel<<<(N_NODES + 127) / 128, 256, 0, stream>>>(x, W1, dinv, hs);
    agg1_kernel<<<(N_NODES + 7) / 8, 256, 0, stream>>>(row_ptr, col, (const __half2*)hs,
                                                       dinv, b1, h2);

    // layer 2
    gemm2_kernel<<<(N_NODES + 127) / 128, 256, 0, stream>>>(h2, W2, dinv, gs);
    agg2_kernel<<<(N_NODES + 15) / 16, 256, 0, stream>>>(row_ptr, col, (const __half2*)gs,
                                                         dinv, b2, out);
}